// Round 14
// baseline (250.422 us; speedup 1.0000x reference)
//
#include <hip/hip_runtime.h>
#include <hip/hip_fp16.h>

// DGCF single-layer, 2 routing iters (MI355X). fp32 in / fp32 out.
// R28 = R27 with one fix: zat phase-B head lookup.
// R27 post-mortem: slicing DID cut zat traffic (FETCH 151->45MB) but zat
// went latency-bound (HBM 12%, 56.5us): the 32-node binary search over
// LDS soff[] is 5 DEPENDENT LDS loads (~600cyc serialized per edge,
// ~1.7 edges/thread -> no cross-iteration pipelining). R24's linear form
// had INDEPENDENT compares -- R26 silently made them a chain.
// Fix: hoist soff[1..31] into registers once (static-indexed unroll, one
// latency window), per-edge hl = 31 independent VALU compares. VGPR
// ~12->~50, still >=8 waves/SIMD.
// Everything else byte-identical to R27 (zat planar pinned slices, half
// planar dotq, combine -> interleaved s4 + dcol1, R25-form single-visit
// outk over Xh, rank-from-count scatter, scans).

#define NUSERS 30000
#define NN     60000
#define NNP    (NN + 1)
#define EE     800000
#define SCAN_B ((NN + 255) / 256)       // 235 scan blocks
#define EV_B   ((EE / 4 + 255) / 256)   // 782 int4 edge blocks
#define NW1_B  ((NN + 1 + 3) / 4)       // 15001 prep node blocks (incl zero row)
#define NW_B   ((NN + 3) / 4)           // 15000 combine blocks
#define N8_B   (NN / 8)                 // 7500 outk blocks (8 nodes; 8 | NN)
#define GPI    ((NN + 31) / 32)         // 1875 node-group32s per intent
#define PIN_B  ((((GPI + 1) / 2) * 8))  // 7504 pinned zat blocks

__device__ __forceinline__ float getX(const float* __restrict__ Gu,
                                      const float* __restrict__ Gi,
                                      int n, int c) {
    return (n < NUSERS) ? Gu[n * 64 + c] : Gi[(n - NUSERS) * 64 + c];
}

__device__ __forceinline__ int clampN(int n) {
    return ((unsigned)n < (unsigned)NN) ? n : 0;
}

__device__ __forceinline__ __half2 bch2(float f) {
    return __builtin_bit_cast(__half2, f);
}

// ---- CSR build ----

__global__ void edge_count(const int* __restrict__ eh, int* __restrict__ deg0,
                           int* __restrict__ rank) {
    int e4 = (blockIdx.x * blockDim.x + threadIdx.x) * 4;
    if (e4 >= EE) return;
    int4 h = *(const int4*)(eh + e4);
    int4 r;
    r.x = atomicAdd(&deg0[clampN(h.x)], 1);
    r.y = atomicAdd(&deg0[clampN(h.y)], 1);
    r.z = atomicAdd(&deg0[clampN(h.z)], 1);
    r.w = atomicAdd(&deg0[clampN(h.w)], 1);
    *(int4*)(rank + e4) = r;
}

// In-block exclusive scan of 256 ints; also writes d0a (free: deg0 loaded).
__global__ void scan_local(const int* __restrict__ deg0, int* __restrict__ offsets,
                           int* __restrict__ bsum, float* __restrict__ d0a) {
    int gid = blockIdx.x * 256 + threadIdx.x;
    int lane = threadIdx.x & 63, w = threadIdx.x >> 6;
    int vdeg = (gid < NN) ? deg0[gid] : 0;
    if (gid < NN) d0a[gid] = rsqrtf(fmaxf(0.25f * (float)vdeg, 1e-30f));
    if (gid == NN) d0a[NN] = 0.f;               // zero row
    int x = vdeg;
    #pragma unroll
    for (int d = 1; d < 64; d <<= 1) {
        int y = __shfl_up(x, d, 64);
        if (lane >= d) x += y;
    }
    __shared__ int wsum[4];
    if (lane == 63) wsum[w] = x;
    __syncthreads();
    int wpre = 0;
    #pragma unroll
    for (int j = 0; j < 4; ++j) wpre += (j < w) ? wsum[j] : 0;
    int incl = x + wpre;
    if (gid < NN) offsets[gid] = incl - vdeg;
    if (threadIdx.x == 255) bsum[blockIdx.x] = incl;
}

// merged: scan_add2 (blocks [0,SCAN_B)) || prep tables (rest).
// prep: planar Yq[i][n][16] = d0*X, Tq[i][n][16] = tanh; interleaved
// Xh[n][64] = X (for outk's single-visit full-line gathers).
__global__ void scanadd2_prep(int* __restrict__ offsets, const int* __restrict__ bsum,
                              const float* __restrict__ d0a,
                              const float* __restrict__ Gu, const float* __restrict__ Gi,
                              __half* __restrict__ Yq, __half* __restrict__ Tq,
                              __half* __restrict__ Xh) {
    if (blockIdx.x < SCAN_B) {
        int tid = threadIdx.x, lane = tid & 63, w = tid >> 6;
        int vv = (tid < SCAN_B) ? bsum[tid] : 0;
        int x = vv;
        #pragma unroll
        for (int d = 1; d < 64; d <<= 1) {
            int y = __shfl_up(x, d, 64);
            if (lane >= d) x += y;
        }
        __shared__ int wsum[4];
        __shared__ int bpre;
        if (lane == 63) wsum[w] = x;
        __syncthreads();
        int wpre = 0;
        #pragma unroll
        for (int j = 0; j < 4; ++j) wpre += (j < w) ? wsum[j] : 0;
        if (tid == blockIdx.x) bpre = x + wpre - vv;
        __syncthreads();
        int gid = blockIdx.x * 256 + tid;
        if (gid < NN) offsets[gid] += bpre;
        if (gid == 0) offsets[NN] = EE;
    } else {
        int n = (blockIdx.x - SCAN_B) * 4 + (threadIdx.x >> 6);
        if (n > NN) return;                     // zero row at n == NN
        int lane = threadIdx.x & 63;            // lane == channel
        int i = lane >> 4, cl = lane & 15;
        float x = (n < NN) ? getX(Gu, Gi, n, lane) : 0.f;
        float sx = x * x;
        #pragma unroll
        for (int m = 1; m < 16; m <<= 1) sx += __shfl_xor(sx, m, 64);  // intent group
        float invx = rsqrtf(fmaxf(sx, 1e-12f));
        float d0v = d0a[n];                     // broadcast (d0a[NN]=0)
        size_t a = ((size_t)i * NNP + n) * 16 + cl;
        Yq[a] = __float2half(d0v * x);
        Tq[a] = __float2half(tanhf(x * invx));
        Xh[(size_t)n * 64 + lane] = __float2half(x);
    }
}

// ---- scatter: atomic-free permute; ONE scattered 4B (tail) store/edge ----
__global__ void scatter(const int* __restrict__ eh, const int* __restrict__ et,
                        const int* __restrict__ rank, const int* __restrict__ offsets,
                        int* __restrict__ csr_tail) {
    int e4 = (blockIdx.x * 256 + threadIdx.x) * 4;
    if (e4 >= EE) return;
    int4 h = *(const int4*)(eh + e4);
    int4 t = *(const int4*)(et + e4);
    int4 r = *(const int4*)(rank + e4);
    int s0 = offsets[clampN(h.x)] + r.x;
    if ((unsigned)s0 < EE) csr_tail[s0] = clampN(t.x);
    int s1 = offsets[clampN(h.y)] + r.y;
    if ((unsigned)s1 < EE) csr_tail[s1] = clampN(t.y);
    int s2 = offsets[clampN(h.z)] + r.z;
    if ((unsigned)s2 < EE) csr_tail[s2] = clampN(t.z);
    int s3 = offsets[clampN(h.w)] + r.w;
    if ((unsigned)s3 < EE) csr_tail[s3] = clampN(t.w);
}

// ---- zat: pinned per-intent Z-accum + per-edge dot_i (32 nodes/block) ----
__global__ void zat(const int* __restrict__ offsets, const int* __restrict__ csr_tail,
                    const __half* __restrict__ Yq, const __half* __restrict__ Tq,
                    __half* __restrict__ dotq) {
    __shared__ __half zn[32][24];       // 48B row stride (16B-aligned rows)
    __shared__ int soff[33];
    int b = blockIdx.x, tid = threadIdx.x;
    int xcd = b & 7;
    int i = xcd >> 1;                   // intent -> XCD pair (pinned)
    int g = (b >> 3) * 2 + (xcd & 1);
    if (g >= GPI) return;
    int n0 = g * 32;
    if (tid < 33) soff[tid] = offsets[n0 + tid];
    __syncthreads();

    // phase A: 32 nodes x 8 half2-lanes; Z = sum Yq[t] (d0 pre-folded), norm
    {
        int g8 = tid >> 3, cl = tid & 7;
        int s0 = soff[g8], s1 = soff[g8 + 1];
        const __half* Yi = Yq + (size_t)i * NNP * 16;
        float accx = 0.f, accy = 0.f;
        for (int base = s0; base < s1; base += 4) {
            #pragma unroll
            for (int u = 0; u < 4; ++u) {
                int kk = base + u;
                bool act = kk < s1;
                int kc = act ? kk : s0;          // in-bounds; deg >= 1 always
                int t = act ? csr_tail[kc] : NN; // NN = zero row
                __half2 y = *(const __half2*)(Yi + (size_t)t * 16 + cl * 2);
                float2 yf = __half22float2(y);
                accx += yf.x; accy += yf.y;
            }
        }
        float ss = accx * accx + accy * accy;
        ss += __shfl_xor(ss, 1, 64);
        ss += __shfl_xor(ss, 2, 64);
        ss += __shfl_xor(ss, 4, 64);             // 8-lane group = this intent
        float inv = rsqrtf(fmaxf(ss, 1e-12f));
        *(__half2*)&zn[g8][cl * 2] = __floats2half2_rn(accx * inv, accy * inv);
    }
    __syncthreads();

    // Hoist soff[1..31] into REGISTERS (one LDS latency window, static
    // indices -> stays in VGPRs). Per-edge head lookup becomes 31
    // independent VALU compares (R27's binary search was 5 DEPENDENT LDS
    // loads ~600cyc serialized per edge).
    int so[32];
    #pragma unroll
    for (int j = 1; j < 32; ++j) so[j] = soff[j];

    // phase B: per-edge dot_i over the block's edge span (L2-resident Tq_i)
    int e0 = soff[0], e1 = soff[32];
    const __half* Ti = Tq + (size_t)i * NNP * 16;
    for (int k = e0 + tid; k < e1; k += 256) {
        int hl = 0;
        #pragma unroll
        for (int j = 1; j < 32; ++j) hl += (k >= so[j]) ? 1 : 0;
        int t = csr_tail[k];
        float4 ta = *(const float4*)(Ti + (size_t)t * 16);
        float4 tb = *(const float4*)(Ti + (size_t)t * 16 + 8);
        float4 za = *(const float4*)&zn[hl][0];
        float4 zb = *(const float4*)&zn[hl][8];
        __half2 acc = __floats2half2_rn(0.f, 0.f);
        acc = __hfma2(bch2(za.x), bch2(ta.x), acc);
        acc = __hfma2(bch2(za.y), bch2(ta.y), acc);
        acc = __hfma2(bch2(za.z), bch2(ta.z), acc);
        acc = __hfma2(bch2(za.w), bch2(ta.w), acc);
        acc = __hfma2(bch2(zb.x), bch2(tb.x), acc);
        acc = __hfma2(bch2(zb.y), bch2(tb.y), acc);
        acc = __hfma2(bch2(zb.z), bch2(tb.z), acc);
        acc = __hfma2(bch2(zb.w), bch2(tb.w), acc);
        float2 f = __half22float2(acc);
        dotq[(size_t)i * EE + k] = __float2half(f.x + f.y);
    }
}

// ---- combine: softmax over 4 planar dots -> interleaved s4 + dcol1 ----
__global__ void combine(const int* __restrict__ offsets, const __half* __restrict__ dotq,
                        __half* __restrict__ s4, float* __restrict__ dcol1) {
    int n = blockIdx.x * 4 + (threadIdx.x >> 6);
    if (n >= NN) return;
    int lane = threadIdx.x & 63;
    int s0 = offsets[n], s1 = offsets[n + 1];
    float sum0 = 0.f, sum1 = 0.f, sum2 = 0.f, sum3 = 0.f;
    for (int k = s0 + lane; k < s1; k += 64) {
        float v0 = __half2float(dotq[k]);
        float v1 = __half2float(dotq[EE + k]);
        float v2 = __half2float(dotq[2 * EE + k]);
        float v3 = __half2float(dotq[3 * EE + k]);
        float mx = fmaxf(fmaxf(v0, v1), fmaxf(v2, v3));
        float e0 = __expf(v0 - mx), e1 = __expf(v1 - mx);
        float e2 = __expf(v2 - mx), e3 = __expf(v3 - mx);
        float inv = 1.f / (e0 + e1 + e2 + e3);
        e0 *= inv; e1 *= inv; e2 *= inv; e3 *= inv;
        __half2 q01 = __floats2half2_rn(e0, e1);
        __half2 q23 = __floats2half2_rn(e2, e3);
        int2 st;
        st.x = __builtin_bit_cast(int, q01);
        st.y = __builtin_bit_cast(int, q23);
        *(int2*)(s4 + (size_t)k * 4) = st;
        sum0 += e0; sum1 += e1; sum2 += e2; sum3 += e3;
    }
    #pragma unroll
    for (int m = 1; m < 64; m <<= 1) {
        sum0 += __shfl_xor(sum0, m, 64);
        sum1 += __shfl_xor(sum1, m, 64);
        sum2 += __shfl_xor(sum2, m, 64);
        sum3 += __shfl_xor(sum3, m, 64);
    }
    if (lane < 4) {
        float ds = (lane == 0) ? sum0 : (lane == 1) ? sum1 : (lane == 2) ? sum2 : sum3;
        dcol1[n * 4 + lane] = rsqrtf(fmaxf(ds, 1e-30f));
    }
}

// ---- output pass: Z2 gather + finalize (R25 verified form) ----
__global__ void outk(const int* __restrict__ offsets, const int* __restrict__ csr_tail,
                     const __half* __restrict__ Xh, const __half* __restrict__ s4,
                     const float* __restrict__ dcol1,
                     const float* __restrict__ Gu, const float* __restrict__ Gi,
                     float* __restrict__ out) {
    int tid = threadIdx.x;
    int n = blockIdx.x * 8 + (tid >> 5);
    if (n >= NN) return;
    int cc = tid & 31;                           // half2-channel (2cc, 2cc+1)
    int i = cc >> 3;                             // intent of this lane's channels
    int s0 = offsets[n], s1 = offsets[n + 1];
    float accx = 0.f, accy = 0.f;
    for (int base = s0; base < s1; base += 4) {
        #pragma unroll
        for (int u = 0; u < 4; ++u) {
            int kk = base + u;
            bool act = kk < s1;
            int kc = act ? kk : s0;              // in-bounds; deg >= 1 always
            int t = csr_tail[kc];
            int2 raw = *(const int2*)(s4 + (size_t)kc * 4);
            int word = (cc & 16) ? raw.y : raw.x;
            unsigned short us = (unsigned short)(word >> ((cc & 8) ? 16 : 0));
            float s = act ? __half2float(__builtin_bit_cast(__half, us)) : 0.f;
            float w = s * dcol1[t * 4 + i];      // s * d1[tail][intent]
            __half2 y = *(const __half2*)(Xh + (size_t)t * 64 + cc * 2);
            float2 yf = __half22float2(y);
            accx = fmaf(w, yf.x, accx);
            accy = fmaf(w, yf.y, accy);
        }
    }
    float d = dcol1[n * 4 + i];
    int ch = cc * 2;
    const float* xr = (n < NUSERS) ? (Gu + (size_t)n * 64 + ch)
                                   : (Gi + (size_t)(n - NUSERS) * 64 + ch);
    float2 x2 = *(const float2*)xr;
    float2 o;
    o.x = 0.5f * (x2.x + d * accx);
    o.y = 0.5f * (x2.y + d * accy);
    *(float2*)(out + (size_t)n * 64 + ch) = o;
}

// ---- launch ----

extern "C" void kernel_launch(void* const* d_in, const int* in_sizes, int n_in,
                              void* d_out, int out_size, void* d_ws, size_t ws_size,
                              hipStream_t stream) {
    const float* Gu = (const float*)d_in[0];
    const float* Gi = (const float*)d_in[1];
    const int* eh = (const int*)d_in[2];
    const int* et = (const int*)d_in[3];
    float* out = (float*)d_out;

    char* p = (char*)d_ws;
    __half* dotq     = (__half*)p;     p += (size_t)EE * 4 * 2;       // 6.4 MB
    __half* s4       = (__half*)p;     p += (size_t)EE * 4 * 2;       // 6.4 MB
    int*    csr_tail = (int*)p;        p += (size_t)EE * 4;           // 3.2 MB
    int*    rank     = (int*)p;        p += (size_t)EE * 4;           // 3.2 MB
    int*    offsets  = (int*)p;        p += ((size_t)NNP * 4 + 15) / 16 * 16;
    int*    deg0     = (int*)p;        p += (size_t)NN * 4;
    int*    bsum     = (int*)p;        p += ((size_t)SCAN_B * 4 + 15) / 16 * 16;
    float*  d0a      = (float*)p;      p += ((size_t)NNP * 4 + 15) / 16 * 16;
    float*  dcol1    = (float*)p;      p += (size_t)NN * 4 * 4;       // 960 KB
    __half* Yq       = (__half*)p;     p += (size_t)4 * NNP * 16 * 2; // 7.68 MB
    __half* Tq       = (__half*)p;     p += (size_t)4 * NNP * 16 * 2; // 7.68 MB
    __half* Xh       = (__half*)p;     // NNP*64*2 = 7.68 MB -> total ~46 MB

    // CSR build
    hipMemsetAsync(deg0, 0, NN * sizeof(int), stream);
    edge_count<<<EV_B, 256, 0, stream>>>(eh, deg0, rank);
    scan_local<<<SCAN_B, 256, 0, stream>>>(deg0, offsets, bsum, d0a);
    // scan finish || table prep (planar Yq/Tq for zat, interleaved Xh for outk)
    scanadd2_prep<<<SCAN_B + NW1_B, 256, 0, stream>>>(offsets, bsum, d0a,
                                                      Gu, Gi, Yq, Tq, Xh);
    scatter<<<EV_B, 256, 0, stream>>>(eh, et, rank, offsets, csr_tail);

    // iter 0: pinned per-intent Z + dots (L2-resident slices), half dots
    zat<<<PIN_B, 256, 0, stream>>>(offsets, csr_tail, Yq, Tq, dotq);

    // softmax -> interleaved s4 + dcol1 (streaming)
    combine<<<NW_B, 256, 0, stream>>>(offsets, dotq, s4, dcol1);

    // iter 1: single-visit full-line propagate + finalize (R25 form)
    outk<<<N8_B, 256, 0, stream>>>(offsets, csr_tail, Xh, s4, dcol1, Gu, Gi, out);
}

// Round 15
// 236.491 us; speedup vs baseline: 1.0589x; 1.0589x over previous
//
#include <hip/hip_runtime.h>
#include <hip/hip_fp16.h>

// DGCF single-layer, 2 routing iters (MI355X). fp32 in / fp32 out.
// R29 = R25 verbatim revert (best measured: 234.9us, Round 11).
// Post-mortems closing the exploration:
//  - R26 (intent-sliced zat + pinned outk): 258.2 — outk 4-visits/edge.
//  - R27 (sliced zat + R25 outk): 245.6 — zat latency-bound on lookup.
//  - R28 (reg-hoisted lookup): 250.4 — 31 VALU compares/edge cost more
//    than the hidden LDS latency they removed (occupancy already hid it).
//  - R22 (coop mega-kernel): 1127us steady — grid.sync flushes 8
//    non-coherent XCD L2s; dispatch bounds ARE the cheap coherence.
//  - R23 (unroll-8): neutral. R20 (write-combine split): neutral.
// R25 structure: count||prep (tanh overlapped with atomics), scan+d0a,
// scan_add2, atomic-free rank scatter, zat (LDS-fused Z+dots+softmax+deg,
// single unified Xh table + scalar d0a), outk (single-visit full-line
// gathers over the same warm Xh, fp32 weights). zat is L2-capacity bound
// (204MB demand vs 15.4MB tables); remaining levers (fp8 tables, cross-
// block Z sharing) are measured or reasoned dead ends at this absmax.

#define NUSERS 30000
#define NN     60000
#define EE     800000
#define SCAN_B ((NN + 255) / 256)       // 235 scan blocks
#define EV_B   ((EE / 4 + 255) / 256)   // 782 int4 edge blocks
#define NW1_B  ((NN + 1 + 3) / 4)       // 15001 prep node blocks (incl zero row)
#define N8_B   (NN / 8)                 // 7500 blocks (8 nodes; 8 | NN)

__device__ __forceinline__ float getX(const float* __restrict__ Gu,
                                      const float* __restrict__ Gi,
                                      int n, int c) {
    return (n < NUSERS) ? Gu[n * 64 + c] : Gi[(n - NUSERS) * 64 + c];
}

__device__ __forceinline__ int clampN(int n) {
    return ((unsigned)n < (unsigned)NN) ? n : 0;
}

__device__ __forceinline__ __half2 bch2(float f) {
    return __builtin_bit_cast(__half2, f);
}

// ---- merged dispatch: edge_count (blocks [0,EV_B)) || prep (rest) ----
// count: degrees + per-edge rank (atomicAdd return), rank stored int4.
// prep: Xh[n][64] = half(X row), Ttab[n][64] = tanh(l2norm-per-intent X).
// prep does NOT read deg0 -> no hazard with counting atomics.
__global__ void count_prep(const int* __restrict__ eh, int* __restrict__ deg0,
                           int* __restrict__ rank,
                           const float* __restrict__ Gu, const float* __restrict__ Gi,
                           __half* __restrict__ Xh, __half* __restrict__ Ttab) {
    if (blockIdx.x < EV_B) {
        int e4 = (blockIdx.x * 256 + threadIdx.x) * 4;
        if (e4 >= EE) return;
        int4 h = *(const int4*)(eh + e4);
        int4 r;
        r.x = atomicAdd(&deg0[clampN(h.x)], 1);
        r.y = atomicAdd(&deg0[clampN(h.y)], 1);
        r.z = atomicAdd(&deg0[clampN(h.z)], 1);
        r.w = atomicAdd(&deg0[clampN(h.w)], 1);
        *(int4*)(rank + e4) = r;
    } else {
        int n = (blockIdx.x - EV_B) * 4 + (threadIdx.x >> 6);
        if (n > NN) return;                     // zero row at n == NN
        int lane = threadIdx.x & 63;            // lane == channel c
        float x = (n < NN) ? getX(Gu, Gi, n, lane) : 0.f;
        float sx = x * x;
        #pragma unroll
        for (int m = 1; m < 16; m <<= 1) sx += __shfl_xor(sx, m, 64);  // 16-ch intent group
        float invx = rsqrtf(fmaxf(sx, 1e-12f));
        size_t a = (size_t)n * 64 + lane;
        Xh[a]   = __float2half(x);
        Ttab[a] = __float2half(tanhf(x * invx));
    }
}

// In-block exclusive scan of 256 ints; also writes d0a (free: deg0 loaded).
__global__ void scan_local(const int* __restrict__ deg0, int* __restrict__ offsets,
                           int* __restrict__ bsum, float* __restrict__ d0a) {
    int gid = blockIdx.x * 256 + threadIdx.x;
    int lane = threadIdx.x & 63, w = threadIdx.x >> 6;
    int vdeg = (gid < NN) ? deg0[gid] : 0;
    if (gid < NN) d0a[gid] = rsqrtf(fmaxf(0.25f * (float)vdeg, 1e-30f));
    if (gid == NN) d0a[NN] = 0.f;               // zero row
    int x = vdeg;
    #pragma unroll
    for (int d = 1; d < 64; d <<= 1) {
        int y = __shfl_up(x, d, 64);
        if (lane >= d) x += y;
    }
    __shared__ int wsum[4];
    if (lane == 63) wsum[w] = x;
    __syncthreads();
    int wpre = 0;
    #pragma unroll
    for (int j = 0; j < 4; ++j) wpre += (j < w) ? wsum[j] : 0;
    int incl = x + wpre;
    if (gid < NN) offsets[gid] = incl - vdeg;
    if (threadIdx.x == 255) bsum[blockIdx.x] = incl;
}

// Each block re-scans the 235 block sums (cheap) and adds its own prefix.
__global__ void scan_add2(int* __restrict__ offsets, const int* __restrict__ bsum) {
    int tid = threadIdx.x, lane = tid & 63, w = tid >> 6;
    int vv = (tid < SCAN_B) ? bsum[tid] : 0;
    int x = vv;
    #pragma unroll
    for (int d = 1; d < 64; d <<= 1) {
        int y = __shfl_up(x, d, 64);
        if (lane >= d) x += y;
    }
    __shared__ int wsum[4];
    __shared__ int bpre;
    if (lane == 63) wsum[w] = x;
    __syncthreads();
    int wpre = 0;
    #pragma unroll
    for (int j = 0; j < 4; ++j) wpre += (j < w) ? wsum[j] : 0;
    if (tid == blockIdx.x) bpre = x + wpre - vv;   // exclusive prefix of this block
    __syncthreads();
    int gid = blockIdx.x * 256 + tid;
    if (gid < NN) offsets[gid] += bpre;
    if (gid == 0) offsets[NN] = EE;
}

// ---- scatter: atomic-free permute; ONE scattered 4B (tail) store/edge ----
__global__ void scatter(const int* __restrict__ eh, const int* __restrict__ et,
                        const int* __restrict__ rank, const int* __restrict__ offsets,
                        int* __restrict__ csr_tail) {
    int e4 = (blockIdx.x * 256 + threadIdx.x) * 4;
    if (e4 >= EE) return;
    int4 h = *(const int4*)(eh + e4);
    int4 t = *(const int4*)(et + e4);
    int4 r = *(const int4*)(rank + e4);
    int s0 = offsets[clampN(h.x)] + r.x;
    if ((unsigned)s0 < EE) csr_tail[s0] = clampN(t.x);
    int s1 = offsets[clampN(h.y)] + r.y;
    if ((unsigned)s1 < EE) csr_tail[s1] = clampN(t.y);
    int s2 = offsets[clampN(h.z)] + r.z;
    if ((unsigned)s2 < EE) csr_tail[s2] = clampN(t.z);
    int s3 = offsets[clampN(h.w)] + r.w;
    if ((unsigned)s3 < EE) csr_tail[s3] = clampN(t.w);
}

// ---- zat: fused Z-accum + per-edge dots/softmax + deg sums (8 nodes) ----
__global__ void zat(const int* __restrict__ offsets, const int* __restrict__ csr_tail,
                    const __half* __restrict__ Xh, const float* __restrict__ d0a,
                    const __half* __restrict__ Ttab,
                    __half* __restrict__ s4, float* __restrict__ dcol1) {
    __shared__ __half zn[8][72];        // 144B row stride (+16B pad: no bank confl)
    __shared__ float ssum[8][4];        // per-node per-intent score sums
    __shared__ int soff[9];
    int tid = threadIdx.x;
    int n0 = blockIdx.x * 8;            // 8 | NN, always full
    if (tid < 9) soff[tid] = offsets[n0 + tid];
    if (tid >= 32 && tid < 64) ssum[(tid - 32) >> 2][tid & 3] = 0.f;
    __syncthreads();

    // phase A: per 32-lane group, accumulate Z = sum d0[t]*Xh[t], norm -> LDS
    {
        int g = tid >> 5, cc = tid & 31;
        int s0 = soff[g], s1 = soff[g + 1];
        float accx = 0.f, accy = 0.f;
        for (int base = s0; base < s1; base += 4) {
            #pragma unroll
            for (int u = 0; u < 4; ++u) {
                int kk = base + u;
                bool act = kk < s1;
                int kc = act ? kk : s0;          // in-bounds; deg >= 1 always
                int t = act ? csr_tail[kc] : NN; // NN = zero row (Xh row = 0)
                float d0v = d0a[t];              // broadcast, L2-resident
                __half2 y = *(const __half2*)(Xh + (size_t)t * 64 + cc * 2);
                float2 yf = __half22float2(y);
                accx = fmaf(d0v, yf.x, accx);
                accy = fmaf(d0v, yf.y, accy);
            }
        }
        float ss = accx * accx + accy * accy;
        ss += __shfl_xor(ss, 1, 64);
        ss += __shfl_xor(ss, 2, 64);
        ss += __shfl_xor(ss, 4, 64);             // 8-lane group = 1 intent
        float inv = rsqrtf(fmaxf(ss, 1e-12f));
        *(__half2*)&zn[g][cc * 2] = __floats2half2_rn(accx * inv, accy * inv);
    }
    __syncthreads();

    // phase B: per-edge dots + softmax over the block's edge span
    int e0 = soff[0], e1 = soff[8];
    for (int k = e0 + tid; k < e1; k += 256) {
        int hl = 0;
        #pragma unroll
        for (int j = 1; j < 8; ++j) hl += (k >= soff[j]) ? 1 : 0;
        int t = csr_tail[k];
        const float4* tp = (const float4*)(Ttab + (size_t)t * 64);
        float dot[4];
        #pragma unroll
        for (int i = 0; i < 4; ++i) {
            float4 za = *(const float4*)&zn[hl][i * 16];
            float4 zb = *(const float4*)&zn[hl][i * 16 + 8];
            float4 ta = tp[2 * i], tb = tp[2 * i + 1];
            __half2 acc = __floats2half2_rn(0.f, 0.f);
            acc = __hfma2(bch2(za.x), bch2(ta.x), acc);
            acc = __hfma2(bch2(za.y), bch2(ta.y), acc);
            acc = __hfma2(bch2(za.z), bch2(ta.z), acc);
            acc = __hfma2(bch2(za.w), bch2(ta.w), acc);
            acc = __hfma2(bch2(zb.x), bch2(tb.x), acc);
            acc = __hfma2(bch2(zb.y), bch2(tb.y), acc);
            acc = __hfma2(bch2(zb.z), bch2(tb.z), acc);
            acc = __hfma2(bch2(zb.w), bch2(tb.w), acc);
            float2 f = __half22float2(acc);
            dot[i] = f.x + f.y;
        }
        float mx = fmaxf(fmaxf(dot[0], dot[1]), fmaxf(dot[2], dot[3]));
        float q0 = __expf(dot[0] - mx), q1 = __expf(dot[1] - mx);
        float q2 = __expf(dot[2] - mx), q3 = __expf(dot[3] - mx);
        float inv = 1.f / (q0 + q1 + q2 + q3);
        q0 *= inv; q1 *= inv; q2 *= inv; q3 *= inv;
        __half2 o01 = __floats2half2_rn(q0, q1);
        __half2 o23 = __floats2half2_rn(q2, q3);
        int2 st;
        st.x = __builtin_bit_cast(int, o01);
        st.y = __builtin_bit_cast(int, o23);
        *(int2*)(s4 + (size_t)k * 4) = st;
        atomicAdd(&ssum[hl][0], q0);
        atomicAdd(&ssum[hl][1], q1);
        atomicAdd(&ssum[hl][2], q2);
        atomicAdd(&ssum[hl][3], q3);
    }
    __syncthreads();

    // phase C: dcol1 from LDS sums
    if (tid < 32) {
        int nn = n0 + (tid >> 2);
        dcol1[nn * 4 + (tid & 3)] = rsqrtf(fmaxf(ssum[tid >> 2][tid & 3], 1e-30f));
    }
}

// ---- output pass: Z2 gather + finalize ----
// wave = 2 nodes x 32 half2-ch lanes. Per edge: broadcast csr_tail + s4 +
// dcol1[t] (L2-resident); 32 lanes gather one full 128B Xh row (shared,
// warm table); y1 = d1[t]*xh computed in fp32 in-register. float2 store.
__global__ void outk(const int* __restrict__ offsets, const int* __restrict__ csr_tail,
                     const __half* __restrict__ Xh, const __half* __restrict__ s4,
                     const float* __restrict__ dcol1,
                     const float* __restrict__ Gu, const float* __restrict__ Gi,
                     float* __restrict__ out) {
    int tid = threadIdx.x;
    int n = blockIdx.x * 8 + (tid >> 5);
    if (n >= NN) return;
    int cc = tid & 31;                           // half2-channel (2cc, 2cc+1)
    int i = cc >> 3;                             // intent of this lane's channels
    int s0 = offsets[n], s1 = offsets[n + 1];
    float accx = 0.f, accy = 0.f;
    for (int base = s0; base < s1; base += 4) {
        #pragma unroll
        for (int u = 0; u < 4; ++u) {
            int kk = base + u;
            bool act = kk < s1;
            int kc = act ? kk : s0;              // in-bounds; deg >= 1 always
            int t = csr_tail[kc];
            int2 raw = *(const int2*)(s4 + (size_t)kc * 4);
            int word = (cc & 16) ? raw.y : raw.x;
            unsigned short us = (unsigned short)(word >> ((cc & 8) ? 16 : 0));
            float s = act ? __half2float(__builtin_bit_cast(__half, us)) : 0.f;
            float w = s * dcol1[t * 4 + i];      // s * d1[tail][intent]
            __half2 y = *(const __half2*)(Xh + (size_t)t * 64 + cc * 2);
            float2 yf = __half22float2(y);
            accx = fmaf(w, yf.x, accx);
            accy = fmaf(w, yf.y, accy);
        }
    }
    float d = dcol1[n * 4 + i];
    int ch = cc * 2;
    const float* xr = (n < NUSERS) ? (Gu + (size_t)n * 64 + ch)
                                   : (Gi + (size_t)(n - NUSERS) * 64 + ch);
    float2 x2 = *(const float2*)xr;
    float2 o;
    o.x = 0.5f * (x2.x + d * accx);
    o.y = 0.5f * (x2.y + d * accy);
    *(float2*)(out + (size_t)n * 64 + ch) = o;
}

// ---- launch ----

extern "C" void kernel_launch(void* const* d_in, const int* in_sizes, int n_in,
                              void* d_out, int out_size, void* d_ws, size_t ws_size,
                              hipStream_t stream) {
    const float* Gu = (const float*)d_in[0];
    const float* Gi = (const float*)d_in[1];
    const int* eh = (const int*)d_in[2];
    const int* et = (const int*)d_in[3];
    float* out = (float*)d_out;

    char* p = (char*)d_ws;
    __half* s4       = (__half*)p;     p += (size_t)EE * 4 * 2;       // 6.4 MB
    int*    csr_tail = (int*)p;        p += (size_t)EE * 4;           // 3.2 MB
    int*    rank     = (int*)p;        p += (size_t)EE * 4;           // 3.2 MB
    int*    offsets  = (int*)p;        p += ((size_t)(NN + 1) * 4 + 15) / 16 * 16;
    int*    deg0     = (int*)p;        p += (size_t)NN * 4;
    int*    bsum     = (int*)p;        p += ((size_t)SCAN_B * 4 + 15) / 16 * 16;
    float*  dcol1    = (float*)p;      p += (size_t)NN * 4 * 4;       // 960 KB
    float*  d0a      = (float*)p;      p += ((size_t)(NN + 1) * 4 + 15) / 16 * 16;
    __half* Xh       = (__half*)p;     p += (size_t)(NN + 1) * 64 * 2; // 7.68 MB
    __half* Ttab     = (__half*)p;     // 7.68 MB -> total ~30 MB

    // CSR build: count (+rank) overlapped with table prep (tanh VALU work)
    hipMemsetAsync(deg0, 0, NN * sizeof(int), stream);
    count_prep<<<EV_B + NW1_B, 256, 0, stream>>>(eh, deg0, rank, Gu, Gi, Xh, Ttab);
    scan_local<<<SCAN_B, 256, 0, stream>>>(deg0, offsets, bsum, d0a);
    scan_add2<<<SCAN_B, 256, 0, stream>>>(offsets, bsum);

    // atomic-free edge permute (tail-only 4B scatter)
    scatter<<<EV_B, 256, 0, stream>>>(eh, et, rank, offsets, csr_tail);

    // fused iter-0: Z-accum (LDS, d0 in-register) + dots/softmax + deg sums
    zat<<<N8_B, 256, 0, stream>>>(offsets, csr_tail, Xh, d0a, Ttab, s4, dcol1);

    // iter 1 propagate + finalize: d1 in-register, shared warm Xh table
    outk<<<N8_B, 256, 0, stream>>>(offsets, csr_tail, Xh, s4, dcol1, Gu, Gi, out);
}